// Round 14
// baseline (118.518 us; speedup 1.0000x reference)
//
#include <hip/hip_runtime.h>
#include <hip/hip_bf16.h>
#include <math.h>

// BarrierNet fused forward, v28.
// v27 (103.7 harness, ~28us kernel, absmax 4.0) = fp8 W2 GEMM. v28 cuts
// the remaining fixed costs:
// (1) NO prep kernel, NO workspace: W2 f32->fp8 conversion happens in the
//     staging loop (read f32 from L2, cvt_pk_fp8, ds_write); W1 bf16
//     A-frags built from global per wave (8 KB, L2-hot). Saves a launch
//     + ws round-trip; also tests whether the harness's 268 MB ws-poison
//     was conditional on ws use.
// (2) ONE stage phase for BOTH heads (64 KB LDS stage, 66 KB total,
//     still 2 blocks/CU at 132<=160 KB): barriers 4 -> 2. stage is
//     read-only between the two heads' GEMMs.
// (3) Parallel constraint build (part p -> obstacles {p,p+4}; part 3 also
//     opponent): serial depth ~175 -> ~70 cy. Single writer per qC entry.
// Numerics identical to v27 (absmax ~4 expected).

typedef unsigned int u32;
typedef unsigned long long u64;
typedef unsigned short u16;
typedef __attribute__((ext_vector_type(8))) short short8;   // 8 bf16 (MFMA A/B)
typedef __attribute__((ext_vector_type(4))) float f32x4;
typedef __attribute__((ext_vector_type(2))) float f32x2;
typedef __attribute__((ext_vector_type(4))) u32 u32x4;

union Frag  { short8 v; u32 u[4]; u32x4 q; };
union F8    { long l; u32 u[2]; };          // 8 fp8 = 2 VGPRs (MFMA fp8 operand)

__device__ __forceinline__ u32 packbf(float a, float b) {
    float2 f2; f2.x = a; f2.y = b;
    __hip_bfloat162 h = __float22bfloat162_rn(f2);   // v_cvt_pk_bf16_f32
    union { __hip_bfloat162 h2; u32 u; } cv; cv.h2 = h;
    return cv.u;
}

// pack 4 f32 -> 4 e4m3 bytes in one u32 (OCP fp8 on gfx950)
__device__ __forceinline__ u32 packfp8x4(float a, float b, float c, float d) {
    u32 r = 0;
    r = (u32)__builtin_amdgcn_cvt_pk_fp8_f32(a, b, (int)r, false);  // bytes 0-1
    r = (u32)__builtin_amdgcn_cvt_pk_fp8_f32(c, d, (int)r, true);   // bytes 2-3
    return r;
}

__device__ const float OBX[8] = { 10.f, 7.07106781186547524f, 6.123234e-16f, -7.07106781186547524f,
                                 -10.f, -7.07106781186547524f, -1.8369702e-15f, 7.07106781186547524f };
__device__ const float OBY[8] = { 0.f, 7.07106781186547524f, 10.f, 7.07106781186547524f,
                                  1.2246468e-15f, -7.07106781186547524f, -10.f, -7.07106781186547524f };

// triu_indices(9,1) pairs packed as 4-bit nibbles in u64 immediates
#define PI0_ 0x2111111100000000ULL
#define PI1_ 0x5544443333322222ULL
#define PI2_ 0x7665ULL
#define PJ0_ 0x3876543287654321ULL
#define PJ1_ 0x7687658765487654ULL
#define PJ2_ 0x8878ULL
__device__ __forceinline__ int unpack4(u64 w0, u64 w1, u64 w2, int t) {
    u64 w = (t < 16) ? w0 : (t < 32) ? w1 : w2;
    return (int)((w >> ((t & 15) * 4)) & 15);
}

// ---------- fused: everything in one kernel ----------
__global__ __launch_bounds__(512)
void barriernet_kernel(const float* __restrict__ x,      // [B,8]
                       const float* __restrict__ meanp,  // [8]
                       const float* __restrict__ stdp,   // [8]
                       const float* __restrict__ W1,     // [256][8]
                       const float* __restrict__ b1,     // [256]
                       const float* __restrict__ W21,    // [128][256]
                       const float* __restrict__ b21,    // [128]
                       const float* __restrict__ W31,    // [2][128]
                       const float* __restrict__ b31,    // [2]
                       const float* __restrict__ W22,    // [128][256]
                       const float* __restrict__ b22,    // [128]
                       const float* __restrict__ W32,    // [2][128]
                       const float* __restrict__ b32,    // [2]
                       float* __restrict__ out, int Btot)
{
    const int tid  = threadIdx.x;
    const int wave = tid >> 6;          // 0..7
    const int lane = tid & 63;
    const int q    = lane >> 4;
    const int m    = lane & 15;
    const int blockRow = blockIdx.x * 128;

    __shared__ u32x4 stage[4096];     // 64 KB: BOTH heads' fp8 B; tail aliases
    __shared__ float lds_p[128][4];   // 2 KB

    // ---- stage + convert W2 (f32 -> e4m3) for both heads: 8 entries/thread.
    // entry fi = blk*64 + lane, blk = wave*8+i: head=blk>>5, kp=(blk>>3)&3,
    // nt=blk&7; n = nt*16+m, k = 2kp*32 + q*8 + j (x) / odd ks at +32 floats.
    #pragma unroll
    for (int i = 0; i < 8; ++i) {
        int blk = wave * 8 + i;
        int hd  = blk >> 5;
        int kp  = (blk >> 3) & 3;
        int nt  = blk & 7;
        const float* W = hd ? W22 : W21;
        const f32x4* s4 = (const f32x4*)(W + (nt * 16 + m) * 256 + kp * 64 + q * 8);
        f32x4 e0 = s4[0], e1 = s4[1];     // ks = 2kp, j0-3 / j4-7
        f32x4 o0 = s4[8], o1 = s4[9];     // ks = 2kp+1 (+32 floats)
        u32x4 o;
        o.x = packfp8x4(e0.x, e0.y, e0.z, e0.w);
        o.y = packfp8x4(e1.x, e1.y, e1.z, e1.w);
        o.z = packfp8x4(o0.x, o0.y, o0.z, o0.w);
        o.w = packfp8x4(o1.x, o1.y, o1.z, o1.w);
        stage[blk * 64 + lane] = o;
    }

    // ---- layer-1 via bf16 MFMA: B-frag from x, A-frags from W1/b1 (L2-hot)
    Frag xB;
    {
        int R0 = blockRow + wave * 16 + m;
        const f32x4* xv0 = (const f32x4*)(x + (R0 < Btot ? R0 : 0) * 8);
        f32x4 xa0 = xv0[0], xb0 = xv0[1];
        if (q == 0) {
            xB.u[0] = packbf(xa0.x, xa0.y);
            xB.u[1] = packbf(xa0.z, xa0.w);
            xB.u[2] = packbf(xb0.x, xb0.y);
            xB.u[3] = packbf(xb0.z, xb0.w);
        } else if (q == 1) {
            xB.u[0] = 0x00003f80u;      // bf16(1.0) at k=8 (bias feature)
            xB.u[1] = 0u; xB.u[2] = 0u; xB.u[3] = 0u;
        } else {
            xB.u[0] = 0u; xB.u[1] = 0u; xB.u[2] = 0u; xB.u[3] = 0u;
        }
    }
    f32x4 hacc[16];
    #pragma unroll
    for (int nt = 0; nt < 16; ++nt) {
        int n = 32 * (nt & 7) + 8 * (m >> 2) + 4 * (nt >> 3) + (m & 3);
        Frag Af;
        Af.u[0] = 0u; Af.u[1] = 0u; Af.u[2] = 0u; Af.u[3] = 0u;
        if (q == 0) {
            const f32x4* wr = (const f32x4*)(W1 + n * 8);
            f32x4 w0 = wr[0], w1 = wr[1];
            Af.u[0] = packbf(w0.x, w0.y);
            Af.u[1] = packbf(w0.z, w0.w);
            Af.u[2] = packbf(w1.x, w1.y);
            Af.u[3] = packbf(w1.z, w1.w);
        } else if (q == 1) {
            Af.u[0] = packbf(b1[n], 0.f);   // k=8 slot = bias
        }
        hacc[nt] = __builtin_amdgcn_mfma_f32_16x16x32_bf16(
            Af.v, xB.v, (f32x4){0.f, 0.f, 0.f, 0.f}, 0, 0, 0);
    }
    // repack to fp8: A8[ks] byte j <- e4m3(relu(hacc[ks + 8*(j>>2)][j&3]))
    F8 A8[8];
    #pragma unroll
    for (int ks = 0; ks < 8; ++ks) {
        A8[ks].u[0] = packfp8x4(fmaxf(hacc[ks][0], 0.f),     fmaxf(hacc[ks][1], 0.f),
                                fmaxf(hacc[ks][2], 0.f),     fmaxf(hacc[ks][3], 0.f));
        A8[ks].u[1] = packfp8x4(fmaxf(hacc[ks + 8][0], 0.f), fmaxf(hacc[ks + 8][1], 0.f),
                                fmaxf(hacc[ks + 8][2], 0.f), fmaxf(hacc[ks + 8][3], 0.f));
    }

    __syncthreads();    // ONE barrier: all stage writes visible

    #pragma unroll 1
    for (int head = 0; head < 2; ++head) {
        const float* b2 = head ? b22 : b21;
        const float* W3 = head ? W32 : W31;
        const float* b3 = head ? b32 : b31;

        f32x4 acc[8];
        #pragma unroll
        for (int nt = 0; nt < 8; ++nt) acc[nt] = (f32x4){0.f, 0.f, 0.f, 0.f};

        const u32x4* hS = stage + head * 2048;
        #pragma unroll
        for (int kp = 0; kp < 4; ++kp) {
            #pragma unroll
            for (int nt = 0; nt < 8; ++nt) {
                u32x4 b = hS[kp * 512 + nt * 64 + lane];
                F8 be; be.u[0] = b.x; be.u[1] = b.y;   // ks = 2kp
                F8 bo; bo.u[0] = b.z; bo.u[1] = b.w;   // ks = 2kp+1
                acc[nt] = __builtin_amdgcn_mfma_f32_16x16x32_fp8_fp8(
                    A8[2 * kp].l, be.l, acc[nt], 0, 0, 0);
                acc[nt] = __builtin_amdgcn_mfma_f32_16x16x32_fp8_fp8(
                    A8[2 * kp + 1].l, bo.l, acc[nt], 0, 0, 0);
            }
        }
        // no barrier between heads: stage is read-only until the tail

        // ---- epilogue: bias+relu+W3 dot, 16-lane reduce, LDS scatter
        float pr0[4], pr1[4];
        #pragma unroll
        for (int rg = 0; rg < 4; ++rg) { pr0[rg] = 0.f; pr1[rg] = 0.f; }
        #pragma unroll
        for (int nt = 0; nt < 8; ++nt) {
            int col = nt * 16 + m;
            float b2c = b2[col];
            float w0c = W3[col];
            float w1c = W3[128 + col];
            #pragma unroll
            for (int rg = 0; rg < 4; ++rg) {
                float rv = fmaxf(acc[nt][rg] + b2c, 0.f);
                pr0[rg] = fmaf(rv, w0c, pr0[rg]);
                pr1[rg] = fmaf(rv, w1c, pr1[rg]);
            }
        }
        #pragma unroll
        for (int rg = 0; rg < 4; ++rg) {
            float v0 = pr0[rg], v1 = pr1[rg];
            #pragma unroll
            for (int off = 1; off < 16; off <<= 1) {
                v0 += __shfl_xor(v0, off, 64);
                v1 += __shfl_xor(v1, off, 64);
            }
            pr0[rg] = v0; pr1[rg] = v1;
        }
        if (m == 0) {
            #pragma unroll
            for (int rg = 0; rg < 4; ++rg) {
                int row = wave * 16 + q * 4 + rg;
                float a0 = pr0[rg] + b3[0];
                float a1 = pr1[rg] + b3[1];
                if (head == 0) {
                    lds_p[row][0] = a0;
                    lds_p[row][1] = a1;
                } else {
                    lds_p[row][2] = 4.f / (1.f + __expf(-a0));
                    lds_p[row][3] = 4.f / (1.f + __expf(-a1));
                }
            }
        }
    }
    __syncthreads();    // all stage reads + lds_p writes done; tail may alias

    // ================= QP tail (stage buffer reused) =================
    f32x4 (*qC)[128]  = (f32x4(*)[128])stage;             // 18 KB
    f32x4 (*res)[128] = (f32x4(*)[128])(stage + 1152);    // 6 KB, after qC

    const int rq   = tid & 127;         // row within block (0..127)
    const int part = tid >> 7;          // 0..3
    const int R    = blockRow + rq;
    float p0 = lds_p[rq][0];
    float p1 = lds_p[rq][1];

    // ---- constraint build, parallel across parts (single writer per entry)
    {
        float s0 = lds_p[rq][2];
        float s1 = lds_p[rq][3];
        const float* xp = x + (R < Btot ? R : 0) * 8;
        f32x4 xv0 = ((const f32x4*)xp)[0];
        f32x4 xv1 = ((const f32x4*)xp)[1];
        const f32x4 sd0 = ((const f32x4*)stdp)[0],  sd1 = ((const f32x4*)stdp)[1];
        const f32x4 mn0 = ((const f32x4*)meanp)[0], mn1 = ((const f32x4*)meanp)[1];
        float px = fmaf(xv0.x, sd0.x, mn0.x);
        float py = fmaf(xv0.y, sd0.y, mn0.y);
        float th = fmaf(xv0.z, sd0.z, mn0.z);
        float v  = fmaf(xv0.w, sd0.w, mn0.w);
        float st = __sinf(th), ct = __cosf(th);
        float vs = v * st, vc = v * ct;
        float sps = s0 + s1, ss = s0 * s1;
        float Lf2b = 2.f * v * v;
        #pragma unroll
        for (int kk = 0; kk < 2; ++kk) {
            int k = part + kk * 4;      // part p builds obstacles p and p+4
            float dx = px - OBX[k], dy = py - OBY[k];
            float bar  = dx * dx + dy * dy - 0.64f;
            float bdot = 2.f * dx * vc + 2.f * dy * vs;
            float gx = 2.f * dx * vs - 2.f * dy * vc;
            float gy = -(2.f * dx * ct + 2.f * dy * st);
            float hk = Lf2b + sps * bdot + ss * bar;
            float ht = hk + 1e-6f * (1.f + fabsf(hk));
            qC[k][rq] = (f32x4){gx, gy, hk, ht};
        }
        if (part == 3) {                // part 3 builds the opponent row
            float ox = fmaf(xv1.x, sd1.x, mn1.x);
            float oy = fmaf(xv1.y, sd1.y, mn1.y);
            float oth= fmaf(xv1.z, sd1.z, mn1.z);
            float ov = fmaf(xv1.w, sd1.w, mn1.w);
            float so = __sinf(oth), co = __cosf(oth);
            float dxo = px - ox, dyo = py - oy;
            float bar_o  = dxo * dxo + dyo * dyo - 0.25f;
            float bdot_o = 2.f * dxo * (vc - ov * co) + 2.f * dyo * (vs - ov * so);
            float Lf2b_o = 2.f * (v * v + ov * ov + 2.f * v * ov * __cosf(th - oth));
            float gx = 2.f * dxo * vs - 2.f * dyo * vc;
            float gy = -(2.f * dxo * ct + 2.f * dyo * st);
            float hk = Lf2b_o + sps * bdot_o + ss * bar_o;
            float ht = hk + 1e-6f * (1.f + fabsf(hk));
            qC[8][rq] = (f32x4){gx, gy, hk, ht};
        }
    }
    __syncthreads();

    // preload the 9 constraints into NAMED registers
    const f32x4 C0 = qC[0][rq], C1 = qC[1][rq], C2 = qC[2][rq];
    const f32x4 C3 = qC[3][rq], C4 = qC[4][rq], C5 = qC[5][rq];
    const f32x4 C6 = qC[6][rq], C7 = qC[7][rq], C8 = qC[8][rq];

    // ---- z0 fast path: unconstrained optimum feasible => global optimum
    const float zx0 = -p0, zy0 = -p1;
    bool z0ok =
        (zx0 * C0.x + zy0 * C0.y <= C0.w) &&
        (zx0 * C1.x + zy0 * C1.y <= C1.w) &&
        (zx0 * C2.x + zy0 * C2.y <= C2.w) &&
        (zx0 * C3.x + zy0 * C3.y <= C3.w) &&
        (zx0 * C4.x + zy0 * C4.y <= C4.w) &&
        (zx0 * C5.x + zy0 * C5.y <= C5.w) &&
        (zx0 * C6.x + zy0 * C6.y <= C6.w) &&
        (zx0 * C7.x + zy0 * C7.y <= C7.w) &&
        (zx0 * C8.x + zy0 * C8.y <= C8.w);

    float bobj = INFINITY;
    float bzx = zx0, bzy = zy0;     // default -> z0
    if (z0ok) {
        if (part == 0)
            bobj = 0.5f * (zx0 * zx0 + zy0 * zy0) + zx0 * p0 + zy0 * p1;
    } else {
        // candidates: 0 unconstrained, 1..9 singles, 10..45 pairs (triu order)
        // 4-way ordered split: [0,12) [12,24) [24,35) [35,46)
        const int c0i = (part == 0) ? 0  : (part == 1) ? 12 : (part == 2) ? 24 : 35;
        const int c1i = (part == 0) ? 12 : (part == 1) ? 24 : (part == 2) ? 35 : 46;
        #pragma unroll 2
        for (int c = c0i; c < c1i; ++c) {
            float zx, zy;
            bool pre;
            if (c == 0) {
                zx = -p0; zy = -p1; pre = true;
            } else if (c <= 9) {
                f32x4 g = qC[c - 1][rq];                 // one ds_read_b128
                float gg  = g.x * g.x + g.y * g.y;
                float lam = (-(g.x * p0 + g.y * p1) - g.z) / (gg + 1e-12f);
                zx = -p0 - lam * g.x;
                zy = -p1 - lam * g.y;
                pre = (lam >= -1e-8f);
            } else {
                int t = c - 10;
                int pi = unpack4(PI0_, PI1_, PI2_, t);   // scalar, no memory
                int pj = unpack4(PJ0_, PJ1_, PJ2_, t);
                f32x4 gi = qC[pi][rq];                   // two ds_read_b128
                f32x4 gj = qC[pj][rq];
                float det = gi.x * gj.y - gi.y * gj.x;
                bool dok = fabsf(det) > 1e-9f;
                float ds = dok ? det : 1.0f;
                float inv = 1.0f / ds;
                zx = (gi.z * gj.y - gj.z * gi.y) * inv;
                zy = (gi.x * gj.z - gj.x * gi.z) * inv;
                float rx = -(zx + p0), ry = -(zy + p1);
                float li = (gj.y * rx - gj.x * ry) * inv;
                float lj = (gi.x * ry - gi.y * rx) * inv;
                pre = dok && (li >= -1e-8f) && (lj >= -1e-8f);
            }
            bool ok = pre;
            ok = ok && (zx * C0.x + zy * C0.y <= C0.w);
            ok = ok && (zx * C1.x + zy * C1.y <= C1.w);
            ok = ok && (zx * C2.x + zy * C2.y <= C2.w);
            ok = ok && (zx * C3.x + zy * C3.y <= C3.w);
            ok = ok && (zx * C4.x + zy * C4.y <= C4.w);
            ok = ok && (zx * C5.x + zy * C5.y <= C5.w);
            ok = ok && (zx * C6.x + zy * C6.y <= C6.w);
            ok = ok && (zx * C7.x + zy * C7.y <= C7.w);
            ok = ok && (zx * C8.x + zy * C8.y <= C8.w);
            float obj = 0.5f * (zx * zx + zy * zy) + zx * p0 + zy * p1;
            if (ok && obj < bobj) { bobj = obj; bzx = zx; bzy = zy; }
        }
    }

    if (part) {
        res[part - 1][rq] = (f32x4){bobj, bzx, bzy, 0.f};
    }
    __syncthreads();
    if (part == 0) {
        #pragma unroll
        for (int pp = 0; pp < 3; ++pp) {
            f32x4 r = res[pp][rq];
            if (r.x < bobj) { bobj = r.x; bzx = r.y; bzy = r.z; }  // strict <, ordered
        }
        if (R < Btot) {
            f32x2 o2; o2.x = bzx; o2.y = bzy;
            ((f32x2*)out)[R] = o2;
        }
    }
}

extern "C" void kernel_launch(void* const* d_in, const int* in_sizes, int n_in,
                              void* d_out, int out_size, void* d_ws, size_t ws_size,
                              hipStream_t stream) {
    const float* x    = (const float*)d_in[0];
    const float* mean = (const float*)d_in[1];
    const float* stdv = (const float*)d_in[2];
    const float* W1   = (const float*)d_in[3];
    const float* b1   = (const float*)d_in[4];
    const float* W21  = (const float*)d_in[5];
    const float* b21  = (const float*)d_in[6];
    const float* W31  = (const float*)d_in[7];
    const float* b31  = (const float*)d_in[8];
    const float* W22  = (const float*)d_in[9];
    const float* b22  = (const float*)d_in[10];
    const float* W32  = (const float*)d_in[11];
    const float* b32  = (const float*)d_in[12];
    int B = in_sizes[0] / 8;
    float* out = (float*)d_out;

    // single launch; no workspace use
    hipLaunchKernelGGL(barriernet_kernel, dim3((B + 127) / 128), dim3(512), 0, stream,
                       x, mean, stdv, W1, b1, W21, b21, W31, b31, W22, b22, W32, b32,
                       out, B);
}

// Round 15
// 103.836 us; speedup vs baseline: 1.1414x; 1.1414x over previous
//
#include <hip/hip_runtime.h>
#include <hip/hip_bf16.h>
#include <math.h>

// BarrierNet fused forward, v29.
// v28 post-mortem: in-kernel W2 conversion de-amortized prep (every block
// re-read 256 KB f32 W2, uncoalesced) -> kernel 28->44us. Fixed harness
// overhead measured stable at ~75us across v26-v28, so kernel time is the
// only lever. v29 = v27 restored (prep kernel + ws + coalesced frag loads)
// + the two v28 pieces that were NOT the cause:
// (1) ONE stage phase for BOTH heads (64 KB stage, 66 KB total, still
//     2 blocks/CU): barriers 4 -> 2; stage read-only between head GEMMs.
// (2) Parallel constraint build (part p -> obstacles {p,p+4}; part 3 the
//     opponent row): serial depth ~175 -> ~70. Single writer per entry.

typedef unsigned int u32;
typedef unsigned long long u64;
typedef unsigned short u16;
typedef __attribute__((ext_vector_type(8))) short short8;   // 8 bf16 (MFMA A/B)
typedef __attribute__((ext_vector_type(4))) float f32x4;
typedef __attribute__((ext_vector_type(2))) float f32x2;
typedef __attribute__((ext_vector_type(4))) u32 u32x4;

union Frag  { short8 v; u32 u[4]; u32x4 q; };
union F8    { long l; u32 u[2]; };          // 8 fp8 = 2 VGPRs (MFMA fp8 operand)

__device__ __forceinline__ u32 packbf(float a, float b) {
    float2 f2; f2.x = a; f2.y = b;
    __hip_bfloat162 h = __float22bfloat162_rn(f2);   // v_cvt_pk_bf16_f32
    union { __hip_bfloat162 h2; u32 u; } cv; cv.h2 = h;
    return cv.u;
}

// pack 4 f32 -> 4 e4m3 bytes in one u32 (OCP fp8 on gfx950)
__device__ __forceinline__ u32 packfp8x4(float a, float b, float c, float d) {
    u32 r = 0;
    r = (u32)__builtin_amdgcn_cvt_pk_fp8_f32(a, b, (int)r, false);  // bytes 0-1
    r = (u32)__builtin_amdgcn_cvt_pk_fp8_f32(c, d, (int)r, true);   // bytes 2-3
    return r;
}

__device__ const float OBX[8] = { 10.f, 7.07106781186547524f, 6.123234e-16f, -7.07106781186547524f,
                                 -10.f, -7.07106781186547524f, -1.8369702e-15f, 7.07106781186547524f };
__device__ const float OBY[8] = { 0.f, 7.07106781186547524f, 10.f, 7.07106781186547524f,
                                  1.2246468e-15f, -7.07106781186547524f, -10.f, -7.07106781186547524f };

// triu_indices(9,1) pairs packed as 4-bit nibbles in u64 immediates
#define PI0_ 0x2111111100000000ULL
#define PI1_ 0x5544443333322222ULL
#define PI2_ 0x7665ULL
#define PJ0_ 0x3876543287654321ULL
#define PJ1_ 0x7687658765487654ULL
#define PJ2_ 0x8878ULL
__device__ __forceinline__ int unpack4(u64 w0, u64 w1, u64 w2, int t) {
    u64 w = (t < 16) ? w0 : (t < 32) ? w1 : w2;
    return (int)((w >> ((t & 15) * 4)) & 15);
}

// ---------- prep (v27 exact) ----------
// idx < 4096: W2{1,2} fp8 frags: idx = head*2048 + kp*512 + nt*64 + lane.
// idx >= 4096: W1pre bf16 A-frags (v26 layout).
__global__ __launch_bounds__(256)
void prep_kernel(const float* __restrict__ W21, const float* __restrict__ W22,
                 const float* __restrict__ W1,  const float* __restrict__ b1,
                 u32* __restrict__ ws)
{
    int idx  = blockIdx.x * 256 + threadIdx.x;      // 0..5119
    if (idx < 4096) {
        int lane = idx & 63;
        int nt   = (idx >> 6) & 7;
        int kp   = (idx >> 9) & 3;
        int head = idx >> 11;
        const float* W = head ? W22 : W21;
        int q  = lane >> 4;
        int n  = nt * 16 + (lane & 15);
        const float* se = W + n * 256 + (2 * kp) * 32 + q * 8;      // ks even
        const float* so = W + n * 256 + (2 * kp + 1) * 32 + q * 8;  // ks odd
        u32x4 o;
        o.x = packfp8x4(se[0], se[1], se[2], se[3]);
        o.y = packfp8x4(se[4], se[5], se[6], se[7]);
        o.z = packfp8x4(so[0], so[1], so[2], so[3]);
        o.w = packfp8x4(so[4], so[5], so[6], so[7]);
        __builtin_nontemporal_store(o, (u32x4*)ws + idx);
    } else {
        int f    = idx - 4096;          // 0..1023
        int nt   = f >> 6;
        int lane = f & 63;
        int q    = lane >> 4;
        int mm   = lane & 15;
        int n = 32 * (nt & 7) + 8 * (mm >> 2) + 4 * (nt >> 3) + (mm & 3);
        u32x4 o = (u32x4){0u, 0u, 0u, 0u};
        if (q == 0) {
            const float* wr = W1 + n * 8;
            o.x = packbf(wr[0], wr[1]);
            o.y = packbf(wr[2], wr[3]);
            o.z = packbf(wr[4], wr[5]);
            o.w = packbf(wr[6], wr[7]);
        } else if (q == 1) {
            o.x = packbf(b1[n], 0.f);   // k=8 slot = bias
        }
        __builtin_nontemporal_store(o, (u32x4*)ws + idx);
    }
}

// ---------- fused: MFMA layer1 + two fp8-MFMA heads + QP tail ----------
__global__ __launch_bounds__(512)
void barriernet_kernel(const float* __restrict__ x,      // [B,8]
                       const float* __restrict__ meanp,  // [8]
                       const float* __restrict__ stdp,   // [8]
                       const float* __restrict__ b21,    // [128]
                       const float* __restrict__ W31,    // [2][128]
                       const float* __restrict__ b31,    // [2]
                       const float* __restrict__ b22,    // [128]
                       const float* __restrict__ W32,    // [2][128]
                       const float* __restrict__ b32,    // [2]
                       const u32* __restrict__ wsB,      // fp8 W2 + bf16 W1pre frags
                       float* __restrict__ out, int Btot)
{
    const int tid  = threadIdx.x;
    const int wave = tid >> 6;          // 0..7
    const int lane = tid & 63;
    const int q    = lane >> 4;
    const int m    = lane & 15;
    const int blockRow = blockIdx.x * 128;

    __shared__ u32x4 stage[4096];     // 64 KB: BOTH heads' fp8 B; tail aliases
    __shared__ float lds_p[128][4];   // 2 KB

    const u32x4* wsB4 = (const u32x4*)wsB;

    // ---- stage BOTH heads' fp8 B in one phase: 4096 u32x4, 8/thread
    #pragma unroll
    for (int i = 0; i < 8; ++i) {
        int fi = (wave * 8 + i) * 64 + lane;
        stage[fi] = wsB4[fi];
    }

    // ---- layer-1 via bf16 MFMA: B-frag from x, A-frags = W1pre from ws
    Frag xB;
    {
        int R0 = blockRow + wave * 16 + m;
        const f32x4* xv0 = (const f32x4*)(x + (R0 < Btot ? R0 : 0) * 8);
        f32x4 xa0 = xv0[0], xb0 = xv0[1];
        if (q == 0) {
            xB.u[0] = packbf(xa0.x, xa0.y);
            xB.u[1] = packbf(xa0.z, xa0.w);
            xB.u[2] = packbf(xb0.x, xb0.y);
            xB.u[3] = packbf(xb0.z, xb0.w);
        } else if (q == 1) {
            xB.u[0] = 0x00003f80u;      // bf16(1.0) at k=8 (bias feature)
            xB.u[1] = 0u; xB.u[2] = 0u; xB.u[3] = 0u;
        } else {
            xB.u[0] = 0u; xB.u[1] = 0u; xB.u[2] = 0u; xB.u[3] = 0u;
        }
    }
    f32x4 hacc[16];
    {
        const u32x4* W1f = wsB4 + 4096;
        #pragma unroll
        for (int nt = 0; nt < 16; ++nt) {
            Frag Af; Af.q = W1f[nt * 64 + lane];
            hacc[nt] = __builtin_amdgcn_mfma_f32_16x16x32_bf16(
                Af.v, xB.v, (f32x4){0.f, 0.f, 0.f, 0.f}, 0, 0, 0);
        }
    }
    // repack to fp8: A8[ks] byte j <- e4m3(relu(hacc[ks + 8*(j>>2)][j&3]))
    F8 A8[8];
    #pragma unroll
    for (int ks = 0; ks < 8; ++ks) {
        A8[ks].u[0] = packfp8x4(fmaxf(hacc[ks][0], 0.f),     fmaxf(hacc[ks][1], 0.f),
                                fmaxf(hacc[ks][2], 0.f),     fmaxf(hacc[ks][3], 0.f));
        A8[ks].u[1] = packfp8x4(fmaxf(hacc[ks + 8][0], 0.f), fmaxf(hacc[ks + 8][1], 0.f),
                                fmaxf(hacc[ks + 8][2], 0.f), fmaxf(hacc[ks + 8][3], 0.f));
    }

    __syncthreads();    // ONE barrier: all stage writes visible

    #pragma unroll 1
    for (int head = 0; head < 2; ++head) {
        const float* b2 = head ? b22 : b21;
        const float* W3 = head ? W32 : W31;
        const float* b3 = head ? b32 : b31;

        f32x4 acc[8];
        #pragma unroll
        for (int nt = 0; nt < 8; ++nt) acc[nt] = (f32x4){0.f, 0.f, 0.f, 0.f};

        const u32x4* hS = stage + head * 2048;
        #pragma unroll
        for (int kp = 0; kp < 4; ++kp) {
            #pragma unroll
            for (int nt = 0; nt < 8; ++nt) {
                u32x4 b = hS[kp * 512 + nt * 64 + lane];
                F8 be; be.u[0] = b.x; be.u[1] = b.y;   // ks = 2kp
                F8 bo; bo.u[0] = b.z; bo.u[1] = b.w;   // ks = 2kp+1
                acc[nt] = __builtin_amdgcn_mfma_f32_16x16x32_fp8_fp8(
                    A8[2 * kp].l, be.l, acc[nt], 0, 0, 0);
                acc[nt] = __builtin_amdgcn_mfma_f32_16x16x32_fp8_fp8(
                    A8[2 * kp + 1].l, bo.l, acc[nt], 0, 0, 0);
            }
        }
        // no barrier between heads: stage is read-only until the tail

        // ---- epilogue: bias+relu+W3 dot, 16-lane reduce, LDS scatter
        float pr0[4], pr1[4];
        #pragma unroll
        for (int rg = 0; rg < 4; ++rg) { pr0[rg] = 0.f; pr1[rg] = 0.f; }
        #pragma unroll
        for (int nt = 0; nt < 8; ++nt) {
            int col = nt * 16 + m;
            float b2c = b2[col];
            float w0c = W3[col];
            float w1c = W3[128 + col];
            #pragma unroll
            for (int rg = 0; rg < 4; ++rg) {
                float rv = fmaxf(acc[nt][rg] + b2c, 0.f);
                pr0[rg] = fmaf(rv, w0c, pr0[rg]);
                pr1[rg] = fmaf(rv, w1c, pr1[rg]);
            }
        }
        #pragma unroll
        for (int rg = 0; rg < 4; ++rg) {
            float v0 = pr0[rg], v1 = pr1[rg];
            #pragma unroll
            for (int off = 1; off < 16; off <<= 1) {
                v0 += __shfl_xor(v0, off, 64);
                v1 += __shfl_xor(v1, off, 64);
            }
            pr0[rg] = v0; pr1[rg] = v1;
        }
        if (m == 0) {
            #pragma unroll
            for (int rg = 0; rg < 4; ++rg) {
                int row = wave * 16 + q * 4 + rg;
                float a0 = pr0[rg] + b3[0];
                float a1 = pr1[rg] + b3[1];
                if (head == 0) {
                    lds_p[row][0] = a0;
                    lds_p[row][1] = a1;
                } else {
                    lds_p[row][2] = 4.f / (1.f + __expf(-a0));
                    lds_p[row][3] = 4.f / (1.f + __expf(-a1));
                }
            }
        }
    }
    __syncthreads();    // all stage reads + lds_p writes done; tail may alias

    // ================= QP tail (stage buffer reused) =================
    f32x4 (*qC)[128]  = (f32x4(*)[128])stage;             // 18 KB
    f32x4 (*res)[128] = (f32x4(*)[128])(stage + 1152);    // 6 KB, after qC

    const int rq   = tid & 127;         // row within block (0..127)
    const int part = tid >> 7;          // 0..3
    const int R    = blockRow + rq;
    float p0 = lds_p[rq][0];
    float p1 = lds_p[rq][1];

    // ---- constraint build, parallel across parts (single writer per entry)
    {
        float s0 = lds_p[rq][2];
        float s1 = lds_p[rq][3];
        const float* xp = x + (R < Btot ? R : 0) * 8;
        f32x4 xv0 = ((const f32x4*)xp)[0];
        f32x4 xv1 = ((const f32x4*)xp)[1];
        const f32x4 sd0 = ((const f32x4*)stdp)[0],  sd1 = ((const f32x4*)stdp)[1];
        const f32x4 mn0 = ((const f32x4*)meanp)[0], mn1 = ((const f32x4*)meanp)[1];
        float px = fmaf(xv0.x, sd0.x, mn0.x);
        float py = fmaf(xv0.y, sd0.y, mn0.y);
        float th = fmaf(xv0.z, sd0.z, mn0.z);
        float v  = fmaf(xv0.w, sd0.w, mn0.w);
        float st = __sinf(th), ct = __cosf(th);
        float vs = v * st, vc = v * ct;
        float sps = s0 + s1, ss = s0 * s1;
        float Lf2b = 2.f * v * v;
        #pragma unroll
        for (int kk = 0; kk < 2; ++kk) {
            int k = part + kk * 4;      // part p builds obstacles p and p+4
            float dx = px - OBX[k], dy = py - OBY[k];
            float bar  = dx * dx + dy * dy - 0.64f;
            float bdot = 2.f * dx * vc + 2.f * dy * vs;
            float gx = 2.f * dx * vs - 2.f * dy * vc;
            float gy = -(2.f * dx * ct + 2.f * dy * st);
            float hk = Lf2b + sps * bdot + ss * bar;
            float ht = hk + 1e-6f * (1.f + fabsf(hk));
            qC[k][rq] = (f32x4){gx, gy, hk, ht};
        }
        if (part == 3) {                // part 3 builds the opponent row
            float ox = fmaf(xv1.x, sd1.x, mn1.x);
            float oy = fmaf(xv1.y, sd1.y, mn1.y);
            float oth= fmaf(xv1.z, sd1.z, mn1.z);
            float ov = fmaf(xv1.w, sd1.w, mn1.w);
            float so = __sinf(oth), co = __cosf(oth);
            float dxo = px - ox, dyo = py - oy;
            float bar_o  = dxo * dxo + dyo * dyo - 0.25f;
            float bdot_o = 2.f * dxo * (vc - ov * co) + 2.f * dyo * (vs - ov * so);
            float Lf2b_o = 2.f * (v * v + ov * ov + 2.f * v * ov * __cosf(th - oth));
            float gx = 2.f * dxo * vs - 2.f * dyo * vc;
            float gy = -(2.f * dxo * ct + 2.f * dyo * st);
            float hk = Lf2b_o + sps * bdot_o + ss * bar_o;
            float ht = hk + 1e-6f * (1.f + fabsf(hk));
            qC[8][rq] = (f32x4){gx, gy, hk, ht};
        }
    }
    __syncthreads();

    // preload the 9 constraints into NAMED registers
    const f32x4 C0 = qC[0][rq], C1 = qC[1][rq], C2 = qC[2][rq];
    const f32x4 C3 = qC[3][rq], C4 = qC[4][rq], C5 = qC[5][rq];
    const f32x4 C6 = qC[6][rq], C7 = qC[7][rq], C8 = qC[8][rq];

    // ---- z0 fast path: unconstrained optimum feasible => global optimum
    const float zx0 = -p0, zy0 = -p1;
    bool z0ok =
        (zx0 * C0.x + zy0 * C0.y <= C0.w) &&
        (zx0 * C1.x + zy0 * C1.y <= C1.w) &&
        (zx0 * C2.x + zy0 * C2.y <= C2.w) &&
        (zx0 * C3.x + zy0 * C3.y <= C3.w) &&
        (zx0 * C4.x + zy0 * C4.y <= C4.w) &&
        (zx0 * C5.x + zy0 * C5.y <= C5.w) &&
        (zx0 * C6.x + zy0 * C6.y <= C6.w) &&
        (zx0 * C7.x + zy0 * C7.y <= C7.w) &&
        (zx0 * C8.x + zy0 * C8.y <= C8.w);

    float bobj = INFINITY;
    float bzx = zx0, bzy = zy0;     // default -> z0
    if (z0ok) {
        if (part == 0)
            bobj = 0.5f * (zx0 * zx0 + zy0 * zy0) + zx0 * p0 + zy0 * p1;
    } else {
        // candidates: 0 unconstrained, 1..9 singles, 10..45 pairs (triu order)
        // 4-way ordered split: [0,12) [12,24) [24,35) [35,46)
        const int c0i = (part == 0) ? 0  : (part == 1) ? 12 : (part == 2) ? 24 : 35;
        const int c1i = (part == 0) ? 12 : (part == 1) ? 24 : (part == 2) ? 35 : 46;
        #pragma unroll 2
        for (int c = c0i; c < c1i; ++c) {
            float zx, zy;
            bool pre;
            if (c == 0) {
                zx = -p0; zy = -p1; pre = true;
            } else if (c <= 9) {
                f32x4 g = qC[c - 1][rq];                 // one ds_read_b128
                float gg  = g.x * g.x + g.y * g.y;
                float lam = (-(g.x * p0 + g.y * p1) - g.z) / (gg + 1e-12f);
                zx = -p0 - lam * g.x;
                zy = -p1 - lam * g.y;
                pre = (lam >= -1e-8f);
            } else {
                int t = c - 10;
                int pi = unpack4(PI0_, PI1_, PI2_, t);   // scalar, no memory
                int pj = unpack4(PJ0_, PJ1_, PJ2_, t);
                f32x4 gi = qC[pi][rq];                   // two ds_read_b128
                f32x4 gj = qC[pj][rq];
                float det = gi.x * gj.y - gi.y * gj.x;
                bool dok = fabsf(det) > 1e-9f;
                float ds = dok ? det : 1.0f;
                float inv = 1.0f / ds;
                zx = (gi.z * gj.y - gj.z * gi.y) * inv;
                zy = (gi.x * gj.z - gj.x * gi.z) * inv;
                float rx = -(zx + p0), ry = -(zy + p1);
                float li = (gj.y * rx - gj.x * ry) * inv;
                float lj = (gi.x * ry - gi.y * rx) * inv;
                pre = dok && (li >= -1e-8f) && (lj >= -1e-8f);
            }
            bool ok = pre;
            ok = ok && (zx * C0.x + zy * C0.y <= C0.w);
            ok = ok && (zx * C1.x + zy * C1.y <= C1.w);
            ok = ok && (zx * C2.x + zy * C2.y <= C2.w);
            ok = ok && (zx * C3.x + zy * C3.y <= C3.w);
            ok = ok && (zx * C4.x + zy * C4.y <= C4.w);
            ok = ok && (zx * C5.x + zy * C5.y <= C5.w);
            ok = ok && (zx * C6.x + zy * C6.y <= C6.w);
            ok = ok && (zx * C7.x + zy * C7.y <= C7.w);
            ok = ok && (zx * C8.x + zy * C8.y <= C8.w);
            float obj = 0.5f * (zx * zx + zy * zy) + zx * p0 + zy * p1;
            if (ok && obj < bobj) { bobj = obj; bzx = zx; bzy = zy; }
        }
    }

    if (part) {
        res[part - 1][rq] = (f32x4){bobj, bzx, bzy, 0.f};
    }
    __syncthreads();
    if (part == 0) {
        #pragma unroll
        for (int pp = 0; pp < 3; ++pp) {
            f32x4 r = res[pp][rq];
            if (r.x < bobj) { bobj = r.x; bzx = r.y; bzy = r.z; }  // strict <, ordered
        }
        if (R < Btot) {
            f32x2 o2; o2.x = bzx; o2.y = bzy;
            ((f32x2*)out)[R] = o2;
        }
    }
}

extern "C" void kernel_launch(void* const* d_in, const int* in_sizes, int n_in,
                              void* d_out, int out_size, void* d_ws, size_t ws_size,
                              hipStream_t stream) {
    const float* x    = (const float*)d_in[0];
    const float* mean = (const float*)d_in[1];
    const float* stdv = (const float*)d_in[2];
    const float* W1   = (const float*)d_in[3];
    const float* b1   = (const float*)d_in[4];
    const float* W21  = (const float*)d_in[5];
    const float* b21  = (const float*)d_in[6];
    const float* W31  = (const float*)d_in[7];
    const float* b31  = (const float*)d_in[8];
    const float* W22  = (const float*)d_in[9];
    const float* b22  = (const float*)d_in[10];
    const float* W32  = (const float*)d_in[11];
    const float* b32  = (const float*)d_in[12];
    int B = in_sizes[0] / 8;
    float* out = (float*)d_out;
    u32* ws = (u32*)d_ws;

    // 5120 u32x4 frags total: 4096 W2-fp8 (64 KB) + 1024 W1pre-bf16 (16 KB)
    hipLaunchKernelGGL(prep_kernel, dim3(20), dim3(256), 0, stream,
                       W21, W22, W1, b1, ws);

    hipLaunchKernelGGL(barriernet_kernel, dim3((B + 127) / 128), dim3(512), 0, stream,
                       x, mean, stdv, b21, W31, b31, b22, W32, b32,
                       ws, out, B);
}

// Round 17
// 102.035 us; speedup vs baseline: 1.1615x; 1.0177x over previous
//
#include <hip/hip_runtime.h>
#include <hip/hip_bf16.h>
#include <math.h>

// BarrierNet fused forward, v30 (resubmit -- r16 bench was an infra
// acquisition failure, same as r11; kernel never compiled/ran. One
// hardening change: explicit f32x16 zero constant instead of scalar-splat
// casts. Index algebra re-verified on paper this round.)
// v29 flat vs v27 => only per-row work cuts move this kernel. v30: switch
// the whole pipeline to 32x32 MFMA shapes (32 rows/wave):
//  - GEMM (fp8 32x32x16): each B-frag ds_read serves 32 rows -> per-CU
//    GEMM LDS reads ~1024 -> ~256 (hottest pipe).
//  - layer-1 (bf16 32x32x16, K=16 >= 9): 8 MFMAs per 32 rows (was 32).
//  - epilogue W3-dot as 8 bf16 MFMAs: D2[m=out][n=row] gives each lane its
//    OWN row's 64 out-values in regs; rv->bf16 + W3pre MFMA lands
//    p0/p1 in acc3[0]/acc3[1] of lanes 0-31. ZERO shuffles.
//  - all hidden/out enumerations are free permutations absorbed into prep
//    (W2pre/W1pre/W3pre/b2pre swizzled consistently).
//  - one-shot global_load_lds DMA stage (64 KB, both heads).
// Layouts: A: m=l&31,k=(l>>5)*8+j; B: n=l&31,k=(l>>5)*8+j; C/D: col=l&31,
// row=(r&3)+8(r>>2)+4(l>>5) (guide-verified m74/m101).
// Geometry: 256 thd = 4 waves x 32 rows = 128 rows/block, grid B/128=512,
// LDS 66 KB -> 2 blocks/CU = 8 waves/CU (halved - the accepted risk).

typedef unsigned int u32;
typedef unsigned long long u64;
typedef unsigned short u16;
typedef __attribute__((ext_vector_type(8))) short short8;    // 8 bf16 (4 VGPR)
typedef __attribute__((ext_vector_type(4))) float f32x4;
typedef __attribute__((ext_vector_type(16))) float f32x16;   // 32x32 acc
typedef __attribute__((ext_vector_type(2))) float f32x2;
typedef __attribute__((ext_vector_type(4))) u32 u32x4;

union Frag  { short8 v; u32 u[4]; u32x4 q; };
union F8    { long l; u32 u[2]; };          // 8 fp8 (2 VGPR MFMA operand)

__device__ __forceinline__ f32x16 zero16() {
    f32x16 z = {0.f, 0.f, 0.f, 0.f, 0.f, 0.f, 0.f, 0.f,
                0.f, 0.f, 0.f, 0.f, 0.f, 0.f, 0.f, 0.f};
    return z;
}

// async global->LDS DMA, 16B/lane; lds ptr wave-uniform (lane L -> base+L*16)
#define DMA16(gp, lp)                                                        \
    __builtin_amdgcn_global_load_lds(                                        \
        (const __attribute__((address_space(1))) void*)(gp),                 \
        (__attribute__((address_space(3))) void*)(lp), 16, 0, 0)

__device__ __forceinline__ u32 packbf(float a, float b) {
    float2 f2; f2.x = a; f2.y = b;
    __hip_bfloat162 h = __float22bfloat162_rn(f2);
    union { __hip_bfloat162 h2; u32 u; } cv; cv.h2 = h;
    return cv.u;
}
__device__ __forceinline__ u32 packfp8x4(float a, float b, float c, float d) {
    u32 r = 0;
    r = (u32)__builtin_amdgcn_cvt_pk_fp8_f32(a, b, (int)r, false);
    r = (u32)__builtin_amdgcn_cvt_pk_fp8_f32(c, d, (int)r, true);
    return r;
}

__device__ const float OBX[8] = { 10.f, 7.07106781186547524f, 6.123234e-16f, -7.07106781186547524f,
                                 -10.f, -7.07106781186547524f, -1.8369702e-15f, 7.07106781186547524f };
__device__ const float OBY[8] = { 0.f, 7.07106781186547524f, 10.f, 7.07106781186547524f,
                                  1.2246468e-15f, -7.07106781186547524f, -10.f, -7.07106781186547524f };

#define PI0_ 0x2111111100000000ULL
#define PI1_ 0x5544443333322222ULL
#define PI2_ 0x7665ULL
#define PJ0_ 0x3876543287654321ULL
#define PJ1_ 0x7687658765487654ULL
#define PJ2_ 0x8878ULL
__device__ __forceinline__ int unpack4(u64 w0, u64 w1, u64 w2, int t) {
    u64 w = (t < 16) ? w0 : (t < 32) ? w1 : w2;
    return (int)((w >> ((t & 15) * 4)) & 15);
}

// ---------- prep: ws layout (u32x4 units) ----------
// [0,4096)    W2pre fp8: idx = head*2048 + kp*256 + nt*64 + lane.
//             o = nt*32+(l&31), hi=l>>5. Entry = ks pair {2kp,2kp+1}:
//             u[0]=W2[o][32kp+4hi+0..3] u[1]=[+8..11] u[2]=[+16..19] u[3]=[+24..27]
// [4096,4608) W1pre bf16 A-frags: f=idx-4096: inst=f>>6, lane=f&63;
//             h=inst*32+(l&31); hi=0: k=j -> W1[h][j]; hi=1: j0=b1[h], else 0
// [4608,5632) W3pre bf16 A-frags: f=idx-4608: head=f>>9, kb=(f>>6)&7, lane=f&63;
//             m=l&31 (W3 row if m<2 else 0); o'=32(kb>>1)+16(kb&1)+8(j>>2)+4hi+(j&3)
// [5632,5696) b2pre f32x4: f=idx-5632: head=f>>5, hi=(f>>4)&1, nt=(f>>2)&3, t=f&3;
//             = b2[nt*32 + 8t + 4hi + 0..3]
__global__ __launch_bounds__(256)
void prep_kernel(const float* __restrict__ W21, const float* __restrict__ W22,
                 const float* __restrict__ W1,  const float* __restrict__ b1,
                 const float* __restrict__ W31, const float* __restrict__ W32,
                 const float* __restrict__ b21, const float* __restrict__ b22,
                 u32* __restrict__ ws)
{
    int idx = blockIdx.x * 256 + threadIdx.x;
    if (idx < 4096) {
        int lane = idx & 63;
        int nt   = (idx >> 6) & 3;
        int kp   = (idx >> 8) & 7;
        int head = idx >> 11;
        const float* W = head ? W22 : W21;
        int o  = nt * 32 + (lane & 31);
        int hi = lane >> 5;
        const float* base = W + o * 256 + kp * 32 + hi * 4;
        u32x4 e;
        e.x = packfp8x4(base[0],  base[1],  base[2],  base[3]);
        e.y = packfp8x4(base[8],  base[9],  base[10], base[11]);
        e.z = packfp8x4(base[16], base[17], base[18], base[19]);
        e.w = packfp8x4(base[24], base[25], base[26], base[27]);
        __builtin_nontemporal_store(e, (u32x4*)ws + idx);
    } else if (idx < 4608) {
        int f = idx - 4096;
        int inst = f >> 6, lane = f & 63;
        int hi = lane >> 5;
        int h  = inst * 32 + (lane & 31);
        u32x4 e = (u32x4){0u, 0u, 0u, 0u};
        if (hi == 0) {
            const float* wr = W1 + h * 8;
            e.x = packbf(wr[0], wr[1]);
            e.y = packbf(wr[2], wr[3]);
            e.z = packbf(wr[4], wr[5]);
            e.w = packbf(wr[6], wr[7]);
        } else {
            e.x = packbf(b1[h], 0.f);
        }
        __builtin_nontemporal_store(e, (u32x4*)ws + idx);
    } else if (idx < 5632) {
        int f = idx - 4608;
        int head = f >> 9;
        int kb   = (f >> 6) & 7;
        int lane = f & 63;
        int hi = lane >> 5;
        int mr = lane & 31;
        const float* W3 = head ? W32 : W31;
        int ob = 32 * (kb >> 1) + 16 * (kb & 1) + 4 * hi;
        float v0=0, v1=0, v2=0, v3=0, v4=0, v5=0, v6=0, v7=0;
        if (mr < 2) {
            const float* wr = W3 + mr * 128;
            v0 = wr[ob];     v1 = wr[ob + 1]; v2 = wr[ob + 2]; v3 = wr[ob + 3];
            v4 = wr[ob + 8]; v5 = wr[ob + 9]; v6 = wr[ob + 10]; v7 = wr[ob + 11];
        }
        u32x4 e;
        e.x = packbf(v0, v1); e.y = packbf(v2, v3);
        e.z = packbf(v4, v5); e.w = packbf(v6, v7);
        __builtin_nontemporal_store(e, (u32x4*)ws + idx);
    } else if (idx < 5696) {
        int f = idx - 5632;
        int head = f >> 5, hi = (f >> 4) & 1, nt = (f >> 2) & 3, t = f & 3;
        const float* b2 = head ? b22 : b21;
        int o0 = nt * 32 + 8 * t + 4 * hi;
        f32x4 e; e.x = b2[o0]; e.y = b2[o0+1]; e.z = b2[o0+2]; e.w = b2[o0+3];
        union { f32x4 f; u32x4 u; } cv; cv.f = e;
        __builtin_nontemporal_store(cv.u, (u32x4*)ws + idx);
    }
}

// ---------- fused: 32x32 layer1 + fp8 GEMM + MFMA epilogue + QP tail ----------
__global__ __launch_bounds__(256)
void barriernet_kernel(const float* __restrict__ x,      // [B,8]
                       const float* __restrict__ meanp,  // [8]
                       const float* __restrict__ stdp,   // [8]
                       const float* __restrict__ b31,    // [2]
                       const float* __restrict__ b32,    // [2]
                       const u32* __restrict__ wsB,
                       float* __restrict__ out, int Btot)
{
    const int tid  = threadIdx.x;
    const int wave = tid >> 6;          // 0..3
    const int lane = tid & 63;
    const int hi   = lane >> 5;
    const int ml   = lane & 31;
    const int blockRow = blockIdx.x * 128;

    __shared__ u32x4 stage[4096];     // 64 KB both heads' fp8 W2; tail aliases
    __shared__ float lds_p[128][4];   // 2 KB

    const u32x4* wsB4 = (const u32x4*)wsB;

    // ---- one-shot DMA stage of W2pre (4096 entries); flies under layer-1
    {
        const u32x4* g0 = wsB4 + wave * 1024 + lane;
        u32x4* l0 = stage + wave * 1024;          // wave-uniform base
        #pragma unroll
        for (int i = 0; i < 16; ++i)
            DMA16(g0 + i * 64, l0 + i * 64);
    }

    // ---- layer-1: hid[row=ml][256] via 8 bf16 32x32x16 MFMAs, 2 chunks
    Frag xB;
    {
        int R0 = blockRow + wave * 32 + ml;
        const f32x4* xv0 = (const f32x4*)(x + (R0 < Btot ? R0 : 0) * 8);
        f32x4 xa0 = xv0[0], xb0 = xv0[1];
        if (hi == 0) {
            xB.u[0] = packbf(xa0.x, xa0.y);
            xB.u[1] = packbf(xa0.z, xa0.w);
            xB.u[2] = packbf(xb0.x, xb0.y);
            xB.u[3] = packbf(xb0.z, xb0.w);
        } else {
            xB.u[0] = 0x00003f80u;      // bf16(1.0) at k=8 (bias feature)
            xB.u[1] = 0u; xB.u[2] = 0u; xB.u[3] = 0u;
        }
    }
    // B8[ks].byte[j] = fp8(relu(hacc[ks>>1][j + 8*(ks&1)]))
    F8 B8[16];
    #pragma unroll
    for (int chunk = 0; chunk < 2; ++chunk) {
        f32x16 hacc[4];
        #pragma unroll
        for (int i2 = 0; i2 < 4; ++i2) {
            int inst = chunk * 4 + i2;
            Frag W1f; W1f.q = wsB4[4096 + inst * 64 + lane];
            hacc[i2] = __builtin_amdgcn_mfma_f32_32x32x16_bf16(
                W1f.v, xB.v, zero16(), 0, 0, 0);
        }
        #pragma unroll
        for (int k2 = 0; k2 < 8; ++k2) {
            int ks = chunk * 8 + k2;
            int i2 = k2 >> 1;
            int pb = 8 * (k2 & 1);
            B8[ks].u[0] = packfp8x4(fmaxf(hacc[i2][pb+0], 0.f), fmaxf(hacc[i2][pb+1], 0.f),
                                    fmaxf(hacc[i2][pb+2], 0.f), fmaxf(hacc[i2][pb+3], 0.f));
            B8[ks].u[1] = packfp8x4(fmaxf(hacc[i2][pb+4], 0.f), fmaxf(hacc[i2][pb+5], 0.f),
                                    fmaxf(hacc[i2][pb+6], 0.f), fmaxf(hacc[i2][pb+7], 0.f));
        }
    }

    __syncthreads();    // DMA drained + all waves

    #pragma unroll 1
    for (int head = 0; head < 2; ++head) {
        // ---- GEMM: D2[m=out][n=row]; A = W2pre (LDS), B = B8 (hid)
        f32x16 acc[4];
        #pragma unroll
        for (int nt = 0; nt < 4; ++nt) acc[nt] = zero16();

        const u32x4* hS = stage + head * 2048;
        #pragma unroll
        for (int kp = 0; kp < 8; ++kp) {
            #pragma unroll
            for (int nt = 0; nt < 4; ++nt) {
                u32x4 e = hS[kp * 256 + nt * 64 + lane];
                F8 ae; ae.u[0] = e.x; ae.u[1] = e.y;   // ks = 2kp
                F8 ao; ao.u[0] = e.z; ao.u[1] = e.w;   // ks = 2kp+1
                acc[nt] = __builtin_amdgcn_mfma_f32_32x32x16_fp8_fp8(
                    ae.l, B8[2 * kp].l, acc[nt], 0, 0, 0);
                acc[nt] = __builtin_amdgcn_mfma_f32_32x32x16_fp8_fp8(
                    ao.l, B8[2 * kp + 1].l, acc[nt], 0, 0, 0);
            }
        }

        // ---- epilogue: rv = relu(acc + b2), W3-dot via 8 bf16 MFMAs
        // lane reg r of acc[nt] = out o = nt*32 + (r&3)+8(r>>2)+4hi, row = ml
        const f32x4* b2p = (const f32x4*)(wsB4 + 5632 + head * 32 + hi * 16);
        Frag rvB[8];
        #pragma unroll
        for (int nt = 0; nt < 4; ++nt) {
            f32x4 bq0 = b2p[nt * 4 + 0];
            f32x4 bq1 = b2p[nt * 4 + 1];
            f32x4 bq2 = b2p[nt * 4 + 2];
            f32x4 bq3 = b2p[nt * 4 + 3];
            float rv0  = fmaxf(acc[nt][0]  + bq0.x, 0.f);
            float rv1  = fmaxf(acc[nt][1]  + bq0.y, 0.f);
            float rv2  = fmaxf(acc[nt][2]  + bq0.z, 0.f);
            float rv3  = fmaxf(acc[nt][3]  + bq0.w, 0.f);
            float rv4  = fmaxf(acc[nt][4]  + bq1.x, 0.f);
            float rv5  = fmaxf(acc[nt][5]  + bq1.y, 0.f);
            float rv6  = fmaxf(acc[nt][6]  + bq1.z, 0.f);
            float rv7  = fmaxf(acc[nt][7]  + bq1.w, 0.f);
            float rv8  = fmaxf(acc[nt][8]  + bq2.x, 0.f);
            float rv9  = fmaxf(acc[nt][9]  + bq2.y, 0.f);
            float rv10 = fmaxf(acc[nt][10] + bq2.z, 0.f);
            float rv11 = fmaxf(acc[nt][11] + bq2.w, 0.f);
            float rv12 = fmaxf(acc[nt][12] + bq3.x, 0.f);
            float rv13 = fmaxf(acc[nt][13] + bq3.y, 0.f);
            float rv14 = fmaxf(acc[nt][14] + bq3.z, 0.f);
            float rv15 = fmaxf(acc[nt][15] + bq3.w, 0.f);
            rvB[nt * 2 + 0].u[0] = packbf(rv0,  rv1);
            rvB[nt * 2 + 0].u[1] = packbf(rv2,  rv3);
            rvB[nt * 2 + 0].u[2] = packbf(rv4,  rv5);
            rvB[nt * 2 + 0].u[3] = packbf(rv6,  rv7);
            rvB[nt * 2 + 1].u[0] = packbf(rv8,  rv9);
            rvB[nt * 2 + 1].u[1] = packbf(rv10, rv11);
            rvB[nt * 2 + 1].u[2] = packbf(rv12, rv13);
            rvB[nt * 2 + 1].u[3] = packbf(rv14, rv15);
        }
        f32x16 acc3 = zero16();
        #pragma unroll
        for (int kb = 0; kb < 8; ++kb) {
            Frag W3f; W3f.q = wsB4[4608 + head * 512 + kb * 64 + lane];
            acc3 = __builtin_amdgcn_mfma_f32_32x32x16_bf16(
                W3f.v, rvB[kb].v, acc3, 0, 0, 0);
        }
        // p0/p1 live in acc3[0]/acc3[1] of lanes hi==0 (row = ml)
        if (hi == 0) {
            int row = wave * 32 + ml;
            if (head == 0) {
                lds_p[row][0] = acc3[0] + b31[0];
                lds_p[row][1] = acc3[1] + b31[1];
            } else {
                float a0 = acc3[0] + b32[0];
                float a1 = acc3[1] + b32[1];
                lds_p[row][2] = 4.f / (1.f + __expf(-a0));
                lds_p[row][3] = 4.f / (1.f + __expf(-a1));
            }
        }
    }
    __syncthreads();    // stage reads + lds_p writes done; tail may alias

    // ================= QP tail (stage buffer reused) =================
    f32x4 (*qC)[128]  = (f32x4(*)[128])stage;             // 18 KB
    f32x4 (*res)[128] = (f32x4(*)[128])(stage + 1152);    // 2 KB

    const int rq   = tid & 127;         // row within block
    const int part = tid >> 7;          // 0..1
    const int R    = blockRow + rq;
    float p0 = lds_p[rq][0];
    float p1 = lds_p[rq][1];

    // ---- constraint build: part p -> obstacles {4p..4p+3}; part1 + opponent
    {
        float s0 = lds_p[rq][2];
        float s1 = lds_p[rq][3];
        const float* xp = x + (R < Btot ? R : 0) * 8;
        f32x4 xv0 = ((const f32x4*)xp)[0];
        f32x4 xv1 = ((const f32x4*)xp)[1];
        const f32x4 sd0 = ((const f32x4*)stdp)[0],  sd1 = ((const f32x4*)stdp)[1];
        const f32x4 mn0 = ((const f32x4*)meanp)[0], mn1 = ((const f32x4*)meanp)[1];
        float px = fmaf(xv0.x, sd0.x, mn0.x);
        float py = fmaf(xv0.y, sd0.y, mn0.y);
        float th = fmaf(xv0.z, sd0.z, mn0.z);
        float v  = fmaf(xv0.w, sd0.w, mn0.w);
        float st = __sinf(th), ct = __cosf(th);
        float vs = v * st, vc = v * ct;
        float sps = s0 + s1, ss = s0 * s1;
        float Lf2b = 2.f * v * v;
        #pragma unroll
        for (int kk = 0; kk < 4; ++kk) {
            int k = part * 4 + kk;
            float dx = px - OBX[k], dy = py - OBY[k];
            float bar  = dx * dx + dy * dy - 0.64f;
            float bdot = 2.f * dx * vc + 2.f * dy * vs;
            float gx = 2.f * dx * vs - 2.f * dy * vc;
            float gy = -(2.f * dx * ct + 2.f * dy * st);
            float hk = Lf2b + sps * bdot + ss * bar;
            float ht = hk + 1e-6f * (1.f + fabsf(hk));
            qC[k][rq] = (f32x4){gx, gy, hk, ht};
        }
        if (part == 1) {
            float ox = fmaf(xv1.x, sd1.x, mn1.x);
            float oy = fmaf(xv1.y, sd1.y, mn1.y);
            float oth= fmaf(xv1.z, sd1.z, mn1.z);
            float ov = fmaf(xv1.w, sd1.w, mn1.w);
            float so = __sinf(oth), co = __cosf(oth);
            float dxo = px - ox, dyo = py - oy;
            float bar_o  = dxo * dxo + dyo * dyo - 0.25f;
            float bdot_o = 2.f * dxo * (vc - ov * co) + 2.f * dyo * (vs - ov * so);
            float Lf2b_o = 2.f * (v * v + ov * ov + 2.f * v * ov * __cosf(th - oth));
            float gx = 2.f * dxo * vs - 2.f * dyo * vc;
            float gy = -(2.f * dxo * ct + 2.f * dyo * st);
            float hk = Lf2b_o + sps * bdot_o + ss * bar_o;
            float ht = hk + 1e-6f * (1.f + fabsf(hk));
            qC[8][rq] = (f32x4){gx, gy, hk, ht};
        }
    }
    __syncthreads();

    const f32x4 C0 = qC[0][rq], C1 = qC[1][rq], C2 = qC[2][rq];
    const f32x4 C3 = qC[3][rq], C4 = qC[4][rq], C5 = qC[5][rq];
    const f32x4 C6 = qC[6][rq], C7 = qC[7][rq], C8 = qC[8][rq];

    // ---- z0 fast path: unconstrained optimum feasible => global optimum
    const float zx0 = -p0, zy0 = -p1;
    bool z0ok =
        (zx0 * C0.x + zy0 * C0.y <= C0.w) &&
        (zx0 * C1.x + zy0 * C1.y <= C1.w) &&
        (zx0 * C2.x + zy0 * C2.y <= C2.w) &&
        (zx0 * C3.x + zy0 * C3.y <= C3.w) &&
        (zx0 * C4.x + zy0 * C4.y <= C4.w) &&
        (zx0 * C5.x + zy0 * C5.y <= C5.w) &&
        (zx0 * C6.x + zy0 * C6.y <= C6.w) &&
        (zx0 * C7.x + zy0 * C7.y <= C7.w) &&
        (zx0 * C8.x + zy0 * C8.y <= C8.w);

    float bobj = INFINITY;
    float bzx = zx0, bzy = zy0;
    if (z0ok) {
        if (part == 0)
            bobj = 0.5f * (zx0 * zx0 + zy0 * zy0) + zx0 * p0 + zy0 * p1;
    } else {
        // 2-way ordered split: [0,24) [24,46)
        const int c0i = part ? 24 : 0;
        const int c1i = part ? 46 : 24;
        #pragma unroll 2
        for (int c = c0i; c < c1i; ++c) {
            float zx, zy;
            bool pre;
            if (c == 0) {
                zx = -p0; zy = -p1; pre = true;
            } else if (c <= 9) {
                f32x4 g = qC[c - 1][rq];
                float gg  = g.x * g.x + g.y * g.y;
                float lam = (-(g.x * p0 + g.y * p1) - g.z) / (gg + 1e-12f);
                zx = -p0 - lam * g.x;
                zy = -p1 - lam * g.y;
                pre = (lam >= -1e-8f);
            } else {
                int t = c - 10;
                int pi = unpack4(PI0_, PI1_, PI2_, t);
                int pj = unpack4(PJ0_, PJ1_, PJ2_, t);
                f32x4 gi = qC[pi][rq];
                f32x4 gj = qC[pj][rq];
                float det = gi.x * gj.y - gi.y * gj.x;
                bool dok = fabsf(det) > 1e-9f;
                float ds = dok ? det : 1.0f;
                float inv = 1.0f / ds;
                zx = (gi.z * gj.y - gj.z * gi.y) * inv;
                zy = (gi.x * gj.z - gj.x * gi.z) * inv;
                float rx = -(zx + p0), ry = -(zy + p1);
                float li = (gj.y * rx - gj.x * ry) * inv;
                float lj = (gi.x * ry - gi.y * rx) * inv;
                pre = dok && (li >= -1e-8f) && (lj >= -1e-8f);
            }
            bool ok = pre;
            ok = ok && (zx * C0.x + zy * C0.y <= C0.w);
            ok = ok && (zx * C1.x + zy * C1.y <= C1.w);
            ok = ok && (zx * C2.x + zy * C2.y <= C2.w);
            ok = ok && (zx * C3.x + zy * C3.y <= C3.w);
            ok = ok && (zx * C4.x + zy * C4.y <= C4.w);
            ok = ok && (zx * C5.x + zy * C5.y <= C5.w);
            ok = ok && (zx * C6.x + zy * C6.y <= C6.w);
            ok = ok && (zx * C7.x + zy * C7.y <= C7.w);
            ok = ok && (zx * C8.x + zy * C8.y <= C8.w);
            float obj = 0.5f * (zx * zx + zy * zy) + zx * p0 + zy * p1;
            if (ok && obj < bobj) { bobj = obj; bzx = zx; bzy = zy; }
        }
    }

    if (part) {
        res[0][rq] = (f32x4){bobj, bzx, bzy, 0.f};
    }
    __syncthreads();
    if (part == 0) {
        f32x4 r = res[0][rq];
        if (r.x < bobj) { bobj = r.x; bzx = r.y; bzy = r.z; }
        if (R < Btot) {
            f32x2 o2; o2.x = bzx; o2.y = bzy;
            ((f32x2*)out)[R] = o2;
        }
    }
}

extern "C" void kernel_launch(void* const* d_in, const int* in_sizes, int n_in,
                              void* d_out, int out_size, void* d_ws, size_t ws_size,
                              hipStream_t stream) {
    const float* x    = (const float*)d_in[0];
    const float* mean = (const float*)d_in[1];
    const float* stdv = (const float*)d_in[2];
    const float* W1   = (const float*)d_in[3];
    const float* b1   = (const float*)d_in[4];
    const float* W21  = (const float*)d_in[5];
    const float* b21  = (const float*)d_in[6];
    const float* W31  = (const float*)d_in[7];
    const float* b31  = (const float*)d_in[8];
    const float* W22  = (const float*)d_in[9];
    const float* b22  = (const float*)d_in[10];
    const float* W32  = (const float*)d_in[11];
    const float* b32  = (const float*)d_in[12];
    int B = in_sizes[0] / 8;
    float* out = (float*)d_out;
    u32* ws = (u32*)d_ws;

    // 5696 u32x4 entries: W2pre 4096 + W1pre 512 + W3pre 1024 + b2pre 64
    hipLaunchKernelGGL(prep_kernel, dim3(24), dim3(256), 0, stream,
                       W21, W22, W1, b1, W31, W32, b21, b22, ws);

    hipLaunchKernelGGL(barriernet_kernel, dim3((B + 127) / 128), dim3(256), 0, stream,
                       x, mean, stdv, b31, b32, ws, out, B);
}